// Round 11
// baseline (355.842 us; speedup 1.0000x reference)
//
#include <hip/hip_runtime.h>
#include <stdint.h>

// MissModel: chain of 20 x Linear(64,64) == ONE affine map out = M x + v,
//   M = W19···W0,  v = sum of suffix-products of biases.
// R9: minimal-traffic + high-occupancy apply.
//   R7 (LDS-dense both ways): 80us, 2.5 TB/s, traffic 201 MB, occ 27%.
//   R8 (direct 64B-seg stores): 146us, 3.3 TB/s, traffic 482 MB, occ 52%
//     -> RFO (+143 MB fetch) + write amplification (2x write). Lessons:
//     (1) occupancy raises BW; (2) cached stores need full-line-dense
//     instructions (LDS staging), else RFO+amplification.
//   R9 = R7 store/load structure with 4KB/wave LDS (f32 stage reuses the
//   bf16 region in two 16-token halves) -> 16KB/block, launch_bounds(256,8),
//   2048 blocks x 2 iters -> 8 blocks/CU resident, up to 32 waves/CU.
// prep_split / compose: unchanged from verified R5-R7.

using short8  = __attribute__((ext_vector_type(8))) short;  // 8 bf16
using floatx4 = __attribute__((ext_vector_type(4))) float;  // MFMA 16x16 acc

#define N_TOK   524288
#define N_LAYER 20
// output-feature permutation baked into compose A-frag rows (verified R1-R3)
#define FPERM(mt, m) (32 * ((mt) >> 1) + 8 * ((m) >> 2) + 4 * ((mt) & 1) + ((m) & 3))

#ifdef __has_builtin
#if __has_builtin(__builtin_amdgcn_cvt_pk_bf16_f32)
#define HAVE_CVT_PK_BF16 1
#endif
#endif

#ifdef HAVE_CVT_PK_BF16
typedef __bf16 bf16x2_t __attribute__((ext_vector_type(2)));
__device__ __forceinline__ uint32_t pk_bf16(float lo, float hi) {
  union { bf16x2_t v; uint32_t u; } c;
  c.v = __builtin_amdgcn_cvt_pk_bf16_f32(lo, hi);   // RNE, 1 VALU
  return c.u;
}
#else
__device__ __forceinline__ uint32_t pk_bf16(float lo, float hi) {
  uint32_t a = __float_as_uint(lo) + 0x8000u;
  uint32_t b = __float_as_uint(hi) + 0x8000u;
  return __builtin_amdgcn_perm(b, a, 0x07060302u);
}
#endif

__device__ __forceinline__ float upk_lo(uint32_t p) { return __uint_as_float(p << 16); }
__device__ __forceinline__ float upk_hi(uint32_t p) { return __uint_as_float(p & 0xffff0000u); }

__device__ __forceinline__ uint16_t bf16_rne(float f) {
  uint32_t u = __float_as_uint(f);
  u += 0x7fffu + ((u >> 16) & 1u);
  return (uint16_t)(u >> 16);
}
__device__ __forceinline__ float bf16_dec(uint16_t h) {
  return __uint_as_float(((uint32_t)h) << 16);
}

union BFrag { short8 v; uint32_t u[4]; uint4 raw; };
union AFrag { short8 v; uint32_t u[4]; uint4 raw; };

// ---------------------------------------------------------------------------
// prep_split: W fp32 [20][64][64] -> hi frags (wsh) + residual lo frags (wsl).
// Frag f=mt*2+ks of layer l at [(l*8+f)*64 + lane], 16 B per lane.
// Lane holds A[m=lane&15][k=32*ks+8*(lane>>4)+j], row m = FPERM(mt,m) of W.
// idx space: 20 layers * 8 frags * 64 lanes = 10240.
// ---------------------------------------------------------------------------
__global__ void prep_split(const float* __restrict__ W,
                           uint16_t* __restrict__ wsh, uint16_t* __restrict__ wsl) {
  int idx  = blockIdx.x * 256 + threadIdx.x;   // [0, 10240)
  int l    = idx >> 9;
  int rem  = idx & 511;
  int frag = rem >> 6;
  int lane = rem & 63;
  int mt = frag >> 1, ks = frag & 1;
  int m  = lane & 15;
  int q  = lane >> 4;
  int wrow = FPERM(mt, m);
  const float* src = W + l * 4096 + wrow * 64 + 32 * ks + 8 * q;
  float4 f0 = *(const float4*)(src);
  float4 f1 = *(const float4*)(src + 4);
  float w[8] = {f0.x, f0.y, f0.z, f0.w, f1.x, f1.y, f1.z, f1.w};
  union { uint16_t s[8]; uint4 v; } oh, ol;
  #pragma unroll
  for (int j = 0; j < 8; j++) {
    uint16_t h = bf16_rne(w[j]);
    oh.s[j] = h;
    ol.s[j] = bf16_rne(w[j] - bf16_dec(h));
  }
  *(uint4*)(wsh + (size_t)idx * 8) = oh.v;
  *(uint4*)(wsl + (size_t)idx * 8) = ol.v;
}

// ---------------------------------------------------------------------------
// compose: 1 block, 128 threads. Wave 0 tokens = I_64 columns, wave 1 = 0
// (carries v). Split chain: 3 MFMA products per k-step
// (Wh*Hh + Wh*Hl + Wl*Hh). R2-style prefetch (nf regs -> copy) -- no scratch.
// ---------------------------------------------------------------------------
__global__ __launch_bounds__(128, 1) void compose(
    const uint16_t* __restrict__ wsh, const uint16_t* __restrict__ wsl,
    const float* __restrict__ bias,
    uint16_t* __restrict__ afrag, float* __restrict__ vout)
{
  __shared__ float comp[65][64];                 // comp[t][i]=(M e_t + v)[i]; comp[64]=v
  __shared__ __align__(16) float biasLds[N_LAYER * 64];

  const int tid  = threadIdx.x;
  const int twv  = tid >> 6;
  const int lane = tid & 63;
  const int tl   = lane & 15;
  const int q    = lane >> 4;

  for (int i = tid; i < N_LAYER * 64; i += 128) biasLds[i] = bias[i];

  // basis-vector state (wave0: hi = identity; wave1: zero)
  BFrag Bh[4][2], Bl[4][2];
  #pragma unroll
  for (int tb = 0; tb < 4; tb++) {
    const int tok = twv * 64 + tb * 16 + tl;     // wave1 toks 64..127: never match
    #pragma unroll
    for (int ks = 0; ks < 2; ks++)
      #pragma unroll
      for (int p = 0; p < 4; p++) {
        const int f0 = 32 * ks + 8 * q + 2 * p;
        Bh[tb][ks].u[p] = pk_bf16(tok == f0 ? 1.0f : 0.0f, tok == f0 + 1 ? 1.0f : 0.0f);
        Bl[tb][ks].u[p] = 0u;
      }
  }

  const uint4* wph = (const uint4*)wsh;
  const uint4* wpl = (const uint4*)wsl;

  // layer-0 frags
  AFrag Ah[8], Al[8];
  #pragma unroll
  for (int f = 0; f < 8; f++) {
    Ah[f].raw = wph[f * 64 + lane];
    Al[f].raw = wpl[f * 64 + lane];
  }

  __syncthreads();   // biasLds ready

  floatx4 acc[4][4];
  #pragma unroll 2
  for (int l = 0; l < N_LAYER; l++) {
    const int ln = (l + 1 < N_LAYER) ? l + 1 : N_LAYER - 1;
    uint4 nh[8], nl[8];
    #pragma unroll
    for (int f = 0; f < 8; f++) {
      nh[f] = wph[(ln * 8 + f) * 64 + lane];
      nl[f] = wpl[(ln * 8 + f) * 64 + lane];
    }

    // acc init = bias at permuted positions (same for all tokens: h' = Wh + b)
    #pragma unroll
    for (int mt = 0; mt < 4; mt++) {
      floatx4 bv = *(const floatx4*)(biasLds + l * 64 + 32 * (mt >> 1) + 4 * (mt & 1) + 8 * q);
      #pragma unroll
      for (int tb = 0; tb < 4; tb++) acc[tb][mt] = bv;
    }

    #pragma unroll
    for (int ks = 0; ks < 2; ks++)
      #pragma unroll
      for (int mt = 0; mt < 4; mt++) {
        const int f = mt * 2 + ks;
        #pragma unroll
        for (int tb = 0; tb < 4; tb++) {
          acc[tb][mt] = __builtin_amdgcn_mfma_f32_16x16x32_bf16(Ah[f].v, Bh[tb][ks].v, acc[tb][mt], 0, 0, 0);
          acc[tb][mt] = __builtin_amdgcn_mfma_f32_16x16x32_bf16(Ah[f].v, Bl[tb][ks].v, acc[tb][mt], 0, 0, 0);
          acc[tb][mt] = __builtin_amdgcn_mfma_f32_16x16x32_bf16(Al[f].v, Bh[tb][ks].v, acc[tb][mt], 0, 0, 0);
        }
      }

    if (l == N_LAYER - 1) break;

    // split repack C/D -> next-layer Bh/Bl
    #pragma unroll
    for (int tb = 0; tb < 4; tb++)
      #pragma unroll
      for (int mt = 0; mt < 4; mt++) {
        const int ksn = mt >> 1;
        const int d   = 2 * (mt & 1);
        uint32_t u0 = pk_bf16(acc[tb][mt][0], acc[tb][mt][1]);
        uint32_t u1 = pk_bf16(acc[tb][mt][2], acc[tb][mt][3]);
        Bh[tb][ksn].u[d]     = u0;
        Bh[tb][ksn].u[d + 1] = u1;
        Bl[tb][ksn].u[d]     = pk_bf16(acc[tb][mt][0] - upk_lo(u0), acc[tb][mt][1] - upk_hi(u0));
        Bl[tb][ksn].u[d + 1] = pk_bf16(acc[tb][mt][2] - upk_lo(u1), acc[tb][mt][3] - upk_hi(u1));
      }

    // rotate in prefetched frags (register rename under unroll-2)
    #pragma unroll
    for (int f = 0; f < 8; f++) { Ah[f].raw = nh[f]; Al[f].raw = nl[f]; }
  }

  // epilogue: natural-layout store to LDS, then build apply frags + v
  if (twv == 0) {
    #pragma unroll
    for (int tb = 0; tb < 4; tb++)
      #pragma unroll
      for (int mt = 0; mt < 4; mt++)
        *(floatx4*)&comp[tb * 16 + tl][32 * (mt >> 1) + 4 * (mt & 1) + 8 * q] = acc[tb][mt];
  } else if (tl == 0) {
    #pragma unroll
    for (int mt = 0; mt < 4; mt++)
      *(floatx4*)&comp[64][32 * (mt >> 1) + 4 * (mt & 1) + 8 * q] = acc[0][mt];
  }
  __syncthreads();

  // apply A-frags in IDENTITY row layout: A[m][k] = M[16*mt + m][k];
  // M[i][k] = comp[k][i] - v[i].
  for (int it = tid; it < 512; it += 128) {
    const int f  = it >> 6, ln = it & 63;
    const int mt = f >> 1,  ks = f & 1;
    const int m  = ln & 15, qq = ln >> 4;
    const int r  = 16 * mt + m;
    const float vr = comp[64][r];
    union { uint16_t s[8]; uint4 v; } o;
    #pragma unroll
    for (int j = 0; j < 8; j++) o.s[j] = bf16_rne(comp[32 * ks + 8 * qq + j][r] - vr);
    *(uint4*)(afrag + (size_t)it * 8) = o.v;
  }
  if (tid < 64) vout[tid] = comp[64][tid];
}

// ---------------------------------------------------------------------------
// apply: out = M x + v. R9: LDS-dense both ways + high occupancy.
// Per iteration (32 tokens/wave), 4KB LDS slice per wave:
//   1) 8x global_load_dwordx4 lane-linear (dense 1KB each)
//   2) pk to bf16, 8x ds_write swizzled (region [0,4096))
//   3) 4x ds_read_b128 -> B-frags (P = A ^ (((A>>7)&7)<<4))
//   4) 16 MFMA (identity row layout)
//   5) per 16-token half tb: write acc f32 swizzled into the SAME 4KB
//      (P = A ^ ((tok&7)<<4)), readback lane-linear, 4x dense 1KB stores.
//      In-order per-wave DS pipe + same-pointer aliasing keeps ordering.
// 16KB/block, launch_bounds(256,8), 2048 blocks x 2 iters.
// ---------------------------------------------------------------------------
#define APPLY_BLOCKS 2048

__global__ __launch_bounds__(256, 8) void apply_affine(
    const float* __restrict__ x, const uint16_t* __restrict__ afrag,
    const float* __restrict__ vvec, float* __restrict__ out)
{
  __shared__ __align__(16) uint8_t ldsAll[4][4096];   // 4KB per wave

  const int tid  = threadIdx.x;
  const int wv   = tid >> 6;
  const int lane = tid & 63;
  const int tl   = lane & 15;
  const int q    = lane >> 4;
  uint8_t* lds = ldsAll[wv];

  // M frags (8 KB, L1/L2-broadcast across waves/blocks) -- loaded once
  const uint4* wp = (const uint4*)afrag;
  AFrag Af[8];
  #pragma unroll
  for (int f = 0; f < 8; f++) Af[f].raw = wp[f * 64 + lane];

  // v at identity acc positions
  floatx4 bv[4];
  #pragma unroll
  for (int mt = 0; mt < 4; mt++)
    bv[mt] = *(const floatx4*)(vvec + 16 * mt + 4 * q);

  for (size_t tokbase = (size_t)blockIdx.x * 128 + (size_t)wv * 32;
       tokbase < (size_t)N_TOK;
       tokbase += (size_t)APPLY_BLOCKS * 128) {

    // ---- 1) lane-linear loads: instr j covers bytes [j*1024, j*1024+1024)
    const float* xp = x + tokbase * 64;
    float4 xr[8];
    #pragma unroll
    for (int j = 0; j < 8; j++)
      xr[j] = *(const float4*)(xp + j * 256 + lane * 4);

    // ---- 2) pack + swizzled bf16 stage (region [0,4096): tok*128 + col*2)
    #pragma unroll
    for (int j = 0; j < 8; j++) {
      const uint32_t A = (uint32_t)(j * 512 + lane * 8);
      const uint32_t P = A ^ (((A >> 7) & 7u) << 4);
      uint2 w;
      w.x = pk_bf16(xr[j].x, xr[j].y);
      w.y = pk_bf16(xr[j].z, xr[j].w);
      *(uint2*)(lds + P) = w;
    }

    // ---- 3) B-frags from LDS (cols 32ks+8q..+7 of token tb*16+tl)
    BFrag Bf[2][2];
    #pragma unroll
    for (int tb = 0; tb < 2; tb++)
      #pragma unroll
      for (int ks = 0; ks < 2; ks++) {
        const uint32_t A = (uint32_t)((tb * 16 + tl) * 128 + ks * 64 + q * 16);
        const uint32_t P = A ^ (((A >> 7) & 7u) << 4);
        Bf[tb][ks].raw = *(const uint4*)(lds + P);
      }

    // ---- 4) MFMA
    floatx4 acc[2][4];
    #pragma unroll
    for (int tb = 0; tb < 2; tb++)
      #pragma unroll
      for (int mt = 0; mt < 4; mt++) acc[tb][mt] = bv[mt];

    #pragma unroll
    for (int ks = 0; ks < 2; ks++)
      #pragma unroll
      for (int mt = 0; mt < 4; mt++)
        #pragma unroll
        for (int tb = 0; tb < 2; tb++)
          acc[tb][mt] = __builtin_amdgcn_mfma_f32_16x16x32_bf16(
              Af[mt * 2 + ks].v, Bf[tb][ks].v, acc[tb][mt], 0, 0, 0);

    // ---- 5) per-half f32 stage in the same 4KB slice, then dense stores.
    //      acc[tb][mt][i] = out[tok=tb*16+tl][16*mt + 4*q + i]
    #pragma unroll
    for (int tb = 0; tb < 2; tb++) {
      // write half-tile: local token tl, A = tl*256 + mt*64 + q*16
      #pragma unroll
      for (int mt = 0; mt < 4; mt++) {
        const uint32_t A = (uint32_t)(tl * 256 + mt * 64 + q * 16);
        const uint32_t P = A ^ (((A >> 8) & 7u) << 4);   // XOR by (tok&7)<<4
        *(floatx4*)(lds + P) = acc[tb][mt];
      }
      // readback lane-linear (token j*4+q, cols tl*4..+3) + dense 1KB stores
      float* op = out + (tokbase + tb * 16) * 64;
      #pragma unroll
      for (int j = 0; j < 4; j++) {
        const uint32_t A = (uint32_t)(j * 1024 + lane * 16);
        const uint32_t P = A ^ (((A >> 8) & 7u) << 4);   // (A>>8)&7 = (j*4+q)&7
        floatx4 vdat = *(const floatx4*)(lds + P);
        *(floatx4*)(op + j * 256 + lane * 4) = vdat;
      }
    }
  }
}

extern "C" void kernel_launch(void* const* d_in, const int* in_sizes, int n_in,
                              void* d_out, int out_size, void* d_ws, size_t ws_size,
                              hipStream_t stream) {
  (void)in_sizes; (void)n_in; (void)out_size; (void)ws_size;
  const float* x = (const float*)d_in[0];
  const float* W = (const float*)d_in[1];   // [20][64][64] fp32
  const float* b = (const float*)d_in[2];   // [20][64] fp32
  float* out = (float*)d_out;

  uint16_t* wsh   = (uint16_t*)d_ws;                     // 160 KB hi frags
  uint16_t* wsl   = (uint16_t*)((char*)d_ws + 163840);   // 160 KB lo frags
  uint16_t* afrag = (uint16_t*)((char*)d_ws + 327680);   // 8 KB composed M frags
  float*    vvec  = (float*)((char*)d_ws + 335872);      // 256 B composed v

  prep_split<<<dim3(40), dim3(256), 0, stream>>>(W, wsh, wsl);
  compose<<<dim3(1), dim3(128), 0, stream>>>(wsh, wsl, b, afrag, vvec);
  apply_affine<<<dim3(APPLY_BLOCKS), dim3(256), 0, stream>>>(x, afrag, vvec, out);
}

// Round 12
// 273.084 us; speedup vs baseline: 1.3030x; 1.3030x over previous
//
#include <hip/hip_runtime.h>
#include <stdint.h>

// MissModel: chain of 20 x Linear(64,64) == ONE affine map out = M x + v,
//   M = W19···W0,  v = sum of suffix-products of biases.
// R10: R9 with the register budget fixed (single-variable change).
//   R9 evidence: launch_bounds(256,8) -> VGPR_Count=32 < ~90 live regs
//   -> scratch spill -> FETCH 276MB / WRITE 313MB (spill stream), apply
//   163us despite 70% occupancy and 3.7 TB/s service. Mechanisms now
//   pinned: (1) occupancy raises BW (2.5/3.3/3.7 TB/s @ 27/52/70%);
//   (2) stores must be full-line-dense (R8 RFO); (3) VGPR cap must fit
//   live state (R9 spill). R10 = launch_bounds(256,4) (R7's proven
//   no-spill regime) + R9's 16KB two-half LDS staging + 2048 blocks x 2.
// prep_split / compose: unchanged from verified R5-R9.

using short8  = __attribute__((ext_vector_type(8))) short;  // 8 bf16
using floatx4 = __attribute__((ext_vector_type(4))) float;  // MFMA 16x16 acc

#define N_TOK   524288
#define N_LAYER 20
// output-feature permutation baked into compose A-frag rows (verified R1-R3)
#define FPERM(mt, m) (32 * ((mt) >> 1) + 8 * ((m) >> 2) + 4 * ((mt) & 1) + ((m) & 3))

#ifdef __has_builtin
#if __has_builtin(__builtin_amdgcn_cvt_pk_bf16_f32)
#define HAVE_CVT_PK_BF16 1
#endif
#endif

#ifdef HAVE_CVT_PK_BF16
typedef __bf16 bf16x2_t __attribute__((ext_vector_type(2)));
__device__ __forceinline__ uint32_t pk_bf16(float lo, float hi) {
  union { bf16x2_t v; uint32_t u; } c;
  c.v = __builtin_amdgcn_cvt_pk_bf16_f32(lo, hi);   // RNE, 1 VALU
  return c.u;
}
#else
__device__ __forceinline__ uint32_t pk_bf16(float lo, float hi) {
  uint32_t a = __float_as_uint(lo) + 0x8000u;
  uint32_t b = __float_as_uint(hi) + 0x8000u;
  return __builtin_amdgcn_perm(b, a, 0x07060302u);
}
#endif

__device__ __forceinline__ float upk_lo(uint32_t p) { return __uint_as_float(p << 16); }
__device__ __forceinline__ float upk_hi(uint32_t p) { return __uint_as_float(p & 0xffff0000u); }

__device__ __forceinline__ uint16_t bf16_rne(float f) {
  uint32_t u = __float_as_uint(f);
  u += 0x7fffu + ((u >> 16) & 1u);
  return (uint16_t)(u >> 16);
}
__device__ __forceinline__ float bf16_dec(uint16_t h) {
  return __uint_as_float(((uint32_t)h) << 16);
}

union BFrag { short8 v; uint32_t u[4]; uint4 raw; };
union AFrag { short8 v; uint32_t u[4]; uint4 raw; };

// ---------------------------------------------------------------------------
// prep_split: W fp32 [20][64][64] -> hi frags (wsh) + residual lo frags (wsl).
// Frag f=mt*2+ks of layer l at [(l*8+f)*64 + lane], 16 B per lane.
// Lane holds A[m=lane&15][k=32*ks+8*(lane>>4)+j], row m = FPERM(mt,m) of W.
// idx space: 20 layers * 8 frags * 64 lanes = 10240.
// ---------------------------------------------------------------------------
__global__ void prep_split(const float* __restrict__ W,
                           uint16_t* __restrict__ wsh, uint16_t* __restrict__ wsl) {
  int idx  = blockIdx.x * 256 + threadIdx.x;   // [0, 10240)
  int l    = idx >> 9;
  int rem  = idx & 511;
  int frag = rem >> 6;
  int lane = rem & 63;
  int mt = frag >> 1, ks = frag & 1;
  int m  = lane & 15;
  int q  = lane >> 4;
  int wrow = FPERM(mt, m);
  const float* src = W + l * 4096 + wrow * 64 + 32 * ks + 8 * q;
  float4 f0 = *(const float4*)(src);
  float4 f1 = *(const float4*)(src + 4);
  float w[8] = {f0.x, f0.y, f0.z, f0.w, f1.x, f1.y, f1.z, f1.w};
  union { uint16_t s[8]; uint4 v; } oh, ol;
  #pragma unroll
  for (int j = 0; j < 8; j++) {
    uint16_t h = bf16_rne(w[j]);
    oh.s[j] = h;
    ol.s[j] = bf16_rne(w[j] - bf16_dec(h));
  }
  *(uint4*)(wsh + (size_t)idx * 8) = oh.v;
  *(uint4*)(wsl + (size_t)idx * 8) = ol.v;
}

// ---------------------------------------------------------------------------
// compose: 1 block, 128 threads. Wave 0 tokens = I_64 columns, wave 1 = 0
// (carries v). Split chain: 3 MFMA products per k-step
// (Wh*Hh + Wh*Hl + Wl*Hh). R2-style prefetch (nf regs -> copy) -- no scratch.
// ---------------------------------------------------------------------------
__global__ __launch_bounds__(128, 1) void compose(
    const uint16_t* __restrict__ wsh, const uint16_t* __restrict__ wsl,
    const float* __restrict__ bias,
    uint16_t* __restrict__ afrag, float* __restrict__ vout)
{
  __shared__ float comp[65][64];                 // comp[t][i]=(M e_t + v)[i]; comp[64]=v
  __shared__ __align__(16) float biasLds[N_LAYER * 64];

  const int tid  = threadIdx.x;
  const int twv  = tid >> 6;
  const int lane = tid & 63;
  const int tl   = lane & 15;
  const int q    = lane >> 4;

  for (int i = tid; i < N_LAYER * 64; i += 128) biasLds[i] = bias[i];

  // basis-vector state (wave0: hi = identity; wave1: zero)
  BFrag Bh[4][2], Bl[4][2];
  #pragma unroll
  for (int tb = 0; tb < 4; tb++) {
    const int tok = twv * 64 + tb * 16 + tl;     // wave1 toks 64..127: never match
    #pragma unroll
    for (int ks = 0; ks < 2; ks++)
      #pragma unroll
      for (int p = 0; p < 4; p++) {
        const int f0 = 32 * ks + 8 * q + 2 * p;
        Bh[tb][ks].u[p] = pk_bf16(tok == f0 ? 1.0f : 0.0f, tok == f0 + 1 ? 1.0f : 0.0f);
        Bl[tb][ks].u[p] = 0u;
      }
  }

  const uint4* wph = (const uint4*)wsh;
  const uint4* wpl = (const uint4*)wsl;

  // layer-0 frags
  AFrag Ah[8], Al[8];
  #pragma unroll
  for (int f = 0; f < 8; f++) {
    Ah[f].raw = wph[f * 64 + lane];
    Al[f].raw = wpl[f * 64 + lane];
  }

  __syncthreads();   // biasLds ready

  floatx4 acc[4][4];
  #pragma unroll 2
  for (int l = 0; l < N_LAYER; l++) {
    const int ln = (l + 1 < N_LAYER) ? l + 1 : N_LAYER - 1;
    uint4 nh[8], nl[8];
    #pragma unroll
    for (int f = 0; f < 8; f++) {
      nh[f] = wph[(ln * 8 + f) * 64 + lane];
      nl[f] = wpl[(ln * 8 + f) * 64 + lane];
    }

    // acc init = bias at permuted positions (same for all tokens: h' = Wh + b)
    #pragma unroll
    for (int mt = 0; mt < 4; mt++) {
      floatx4 bv = *(const floatx4*)(biasLds + l * 64 + 32 * (mt >> 1) + 4 * (mt & 1) + 8 * q);
      #pragma unroll
      for (int tb = 0; tb < 4; tb++) acc[tb][mt] = bv;
    }

    #pragma unroll
    for (int ks = 0; ks < 2; ks++)
      #pragma unroll
      for (int mt = 0; mt < 4; mt++) {
        const int f = mt * 2 + ks;
        #pragma unroll
        for (int tb = 0; tb < 4; tb++) {
          acc[tb][mt] = __builtin_amdgcn_mfma_f32_16x16x32_bf16(Ah[f].v, Bh[tb][ks].v, acc[tb][mt], 0, 0, 0);
          acc[tb][mt] = __builtin_amdgcn_mfma_f32_16x16x32_bf16(Ah[f].v, Bl[tb][ks].v, acc[tb][mt], 0, 0, 0);
          acc[tb][mt] = __builtin_amdgcn_mfma_f32_16x16x32_bf16(Al[f].v, Bh[tb][ks].v, acc[tb][mt], 0, 0, 0);
        }
      }

    if (l == N_LAYER - 1) break;

    // split repack C/D -> next-layer Bh/Bl
    #pragma unroll
    for (int tb = 0; tb < 4; tb++)
      #pragma unroll
      for (int mt = 0; mt < 4; mt++) {
        const int ksn = mt >> 1;
        const int d   = 2 * (mt & 1);
        uint32_t u0 = pk_bf16(acc[tb][mt][0], acc[tb][mt][1]);
        uint32_t u1 = pk_bf16(acc[tb][mt][2], acc[tb][mt][3]);
        Bh[tb][ksn].u[d]     = u0;
        Bh[tb][ksn].u[d + 1] = u1;
        Bl[tb][ksn].u[d]     = pk_bf16(acc[tb][mt][0] - upk_lo(u0), acc[tb][mt][1] - upk_hi(u0));
        Bl[tb][ksn].u[d + 1] = pk_bf16(acc[tb][mt][2] - upk_lo(u1), acc[tb][mt][3] - upk_hi(u1));
      }

    // rotate in prefetched frags (register rename under unroll-2)
    #pragma unroll
    for (int f = 0; f < 8; f++) { Ah[f].raw = nh[f]; Al[f].raw = nl[f]; }
  }

  // epilogue: natural-layout store to LDS, then build apply frags + v
  if (twv == 0) {
    #pragma unroll
    for (int tb = 0; tb < 4; tb++)
      #pragma unroll
      for (int mt = 0; mt < 4; mt++)
        *(floatx4*)&comp[tb * 16 + tl][32 * (mt >> 1) + 4 * (mt & 1) + 8 * q] = acc[tb][mt];
  } else if (tl == 0) {
    #pragma unroll
    for (int mt = 0; mt < 4; mt++)
      *(floatx4*)&comp[64][32 * (mt >> 1) + 4 * (mt & 1) + 8 * q] = acc[0][mt];
  }
  __syncthreads();

  // apply A-frags in IDENTITY row layout: A[m][k] = M[16*mt + m][k];
  // M[i][k] = comp[k][i] - v[i].
  for (int it = tid; it < 512; it += 128) {
    const int f  = it >> 6, ln = it & 63;
    const int mt = f >> 1,  ks = f & 1;
    const int m  = ln & 15, qq = ln >> 4;
    const int r  = 16 * mt + m;
    const float vr = comp[64][r];
    union { uint16_t s[8]; uint4 v; } o;
    #pragma unroll
    for (int j = 0; j < 8; j++) o.s[j] = bf16_rne(comp[32 * ks + 8 * qq + j][r] - vr);
    *(uint4*)(afrag + (size_t)it * 8) = o.v;
  }
  if (tid < 64) vout[tid] = comp[64][tid];
}

// ---------------------------------------------------------------------------
// apply: out = M x + v. R10: LDS-dense both ways, no-spill register budget.
// Per iteration (32 tokens/wave), 4KB LDS slice per wave:
//   1) 8x global_load_dwordx4 lane-linear (dense 1KB each)
//   2) pk to bf16, 8x ds_write swizzled (region [0,4096))
//   3) 4x ds_read_b128 -> B-frags (P = A ^ (((A>>7)&7)<<4))
//   4) 16 MFMA (identity row layout)
//   5) per 16-token half tb: write acc f32 swizzled into the SAME 4KB
//      (P = A ^ ((tok&7)<<4)), readback lane-linear, 4x dense 1KB stores.
//      In-order per-wave DS pipe + same-pointer aliasing keeps ordering.
//      (R9-hardware-verified correct.)
// 16KB/block, launch_bounds(256,4) [128-VGPR cap, R7's no-spill regime],
// 2048 blocks x 2 iters.
// ---------------------------------------------------------------------------
#define APPLY_BLOCKS 2048

__global__ __launch_bounds__(256, 4) void apply_affine(
    const float* __restrict__ x, const uint16_t* __restrict__ afrag,
    const float* __restrict__ vvec, float* __restrict__ out)
{
  __shared__ __align__(16) uint8_t ldsAll[4][4096];   // 4KB per wave

  const int tid  = threadIdx.x;
  const int wv   = tid >> 6;
  const int lane = tid & 63;
  const int tl   = lane & 15;
  const int q    = lane >> 4;
  uint8_t* lds = ldsAll[wv];

  // M frags (8 KB, L1/L2-broadcast across waves/blocks) -- loaded once
  const uint4* wp = (const uint4*)afrag;
  AFrag Af[8];
  #pragma unroll
  for (int f = 0; f < 8; f++) Af[f].raw = wp[f * 64 + lane];

  // v at identity acc positions
  floatx4 bv[4];
  #pragma unroll
  for (int mt = 0; mt < 4; mt++)
    bv[mt] = *(const floatx4*)(vvec + 16 * mt + 4 * q);

  for (size_t tokbase = (size_t)blockIdx.x * 128 + (size_t)wv * 32;
       tokbase < (size_t)N_TOK;
       tokbase += (size_t)APPLY_BLOCKS * 128) {

    // ---- 1) lane-linear loads: instr j covers bytes [j*1024, j*1024+1024)
    const float* xp = x + tokbase * 64;
    float4 xr[8];
    #pragma unroll
    for (int j = 0; j < 8; j++)
      xr[j] = *(const float4*)(xp + j * 256 + lane * 4);

    // ---- 2) pack + swizzled bf16 stage (region [0,4096): tok*128 + col*2)
    #pragma unroll
    for (int j = 0; j < 8; j++) {
      const uint32_t A = (uint32_t)(j * 512 + lane * 8);
      const uint32_t P = A ^ (((A >> 7) & 7u) << 4);
      uint2 w;
      w.x = pk_bf16(xr[j].x, xr[j].y);
      w.y = pk_bf16(xr[j].z, xr[j].w);
      *(uint2*)(lds + P) = w;
    }

    // ---- 3) B-frags from LDS (cols 32ks+8q..+7 of token tb*16+tl)
    BFrag Bf[2][2];
    #pragma unroll
    for (int tb = 0; tb < 2; tb++)
      #pragma unroll
      for (int ks = 0; ks < 2; ks++) {
        const uint32_t A = (uint32_t)((tb * 16 + tl) * 128 + ks * 64 + q * 16);
        const uint32_t P = A ^ (((A >> 7) & 7u) << 4);
        Bf[tb][ks].raw = *(const uint4*)(lds + P);
      }

    // ---- 4) MFMA
    floatx4 acc[2][4];
    #pragma unroll
    for (int tb = 0; tb < 2; tb++)
      #pragma unroll
      for (int mt = 0; mt < 4; mt++) acc[tb][mt] = bv[mt];

    #pragma unroll
    for (int ks = 0; ks < 2; ks++)
      #pragma unroll
      for (int mt = 0; mt < 4; mt++)
        #pragma unroll
        for (int tb = 0; tb < 2; tb++)
          acc[tb][mt] = __builtin_amdgcn_mfma_f32_16x16x32_bf16(
              Af[mt * 2 + ks].v, Bf[tb][ks].v, acc[tb][mt], 0, 0, 0);

    // ---- 5) per-half f32 stage in the same 4KB slice, then dense stores.
    //      acc[tb][mt][i] = out[tok=tb*16+tl][16*mt + 4*q + i]
    #pragma unroll
    for (int tb = 0; tb < 2; tb++) {
      // write half-tile: local token tl, A = tl*256 + mt*64 + q*16
      #pragma unroll
      for (int mt = 0; mt < 4; mt++) {
        const uint32_t A = (uint32_t)(tl * 256 + mt * 64 + q * 16);
        const uint32_t P = A ^ (((A >> 8) & 7u) << 4);   // XOR by (tok&7)<<4
        *(floatx4*)(lds + P) = acc[tb][mt];
      }
      // readback lane-linear (token j*4+q, cols tl*4..+3) + dense 1KB stores
      float* op = out + (tokbase + tb * 16) * 64;
      #pragma unroll
      for (int j = 0; j < 4; j++) {
        const uint32_t A = (uint32_t)(j * 1024 + lane * 16);
        const uint32_t P = A ^ (((A >> 8) & 7u) << 4);   // (A>>8)&7 = (j*4+q)&7
        floatx4 vdat = *(const floatx4*)(lds + P);
        *(floatx4*)(op + j * 256 + lane * 4) = vdat;
      }
    }
  }
}

extern "C" void kernel_launch(void* const* d_in, const int* in_sizes, int n_in,
                              void* d_out, int out_size, void* d_ws, size_t ws_size,
                              hipStream_t stream) {
  (void)in_sizes; (void)n_in; (void)out_size; (void)ws_size;
  const float* x = (const float*)d_in[0];
  const float* W = (const float*)d_in[1];   // [20][64][64] fp32
  const float* b = (const float*)d_in[2];   // [20][64] fp32
  float* out = (float*)d_out;

  uint16_t* wsh   = (uint16_t*)d_ws;                     // 160 KB hi frags
  uint16_t* wsl   = (uint16_t*)((char*)d_ws + 163840);   // 160 KB lo frags
  uint16_t* afrag = (uint16_t*)((char*)d_ws + 327680);   // 8 KB composed M frags
  float*    vvec  = (float*)((char*)d_ws + 335872);      // 256 B composed v

  prep_split<<<dim3(40), dim3(256), 0, stream>>>(W, wsh, wsl);
  compose<<<dim3(1), dim3(128), 0, stream>>>(wsh, wsl, b, afrag, vvec);
  apply_affine<<<dim3(APPLY_BLOCKS), dim3(256), 0, stream>>>(x, afrag, vvec, out);
}

// Round 13
// 262.938 us; speedup vs baseline: 1.3533x; 1.0386x over previous
//
#include <hip/hip_runtime.h>
#include <stdint.h>

// MissModel: chain of 20 x Linear(64,64) == ONE affine map out = M x + v.
// R11: register-footprint attack on apply (occupancy model from R7-R10:
//   waves/SIMD = 512/(V+A), realized ~0.69; BW tracks waves 2.5/3.3/3.7
//   TB/s at 27/52/70%). R10's footprint 128 (V64+A~64) -> 4 waves/SIMD.
//   R11 removes the xr[8] staging regs via global_load_lds (async
//   direct-to-LDS), moves bf16 pack after LDS (bit-identical), replaces
//   bv[4] AGPR init with acc=0 + vreg add at store stage.
//   LDS x layout: P = tok*256 + (g ^ (tok&15))*16 (16B granules) --
//   linear gload dest + pre-swizzled per-lane GLOBAL source (rule #21);
//   keeps 1KB-dense global loads AND conflict-free b128 B-frag reads
//   (8 lanes per 4-bank window, derived+checked for all patterns).
//   16 tokens/wave, one-shot 8192 blocks, launch_bounds(256,6) (85-reg
//   budget; peak live ~70). Out staging = R9/R10-hardware-verified math.
// prep_split / compose: unchanged from verified R5-R10.

using short8  = __attribute__((ext_vector_type(8))) short;  // 8 bf16
using floatx4 = __attribute__((ext_vector_type(4))) float;  // MFMA 16x16 acc

#define N_TOK   524288
#define N_LAYER 20
// output-feature permutation baked into compose A-frag rows (verified R1-R3)
#define FPERM(mt, m) (32 * ((mt) >> 1) + 8 * ((m) >> 2) + 4 * ((mt) & 1) + ((m) & 3))

#ifdef __has_builtin
#if __has_builtin(__builtin_amdgcn_cvt_pk_bf16_f32)
#define HAVE_CVT_PK_BF16 1
#endif
#if __has_builtin(__builtin_amdgcn_global_load_lds)
#define HAVE_GLOAD_LDS 1
#endif
#endif

#ifdef HAVE_CVT_PK_BF16
typedef __bf16 bf16x2_t __attribute__((ext_vector_type(2)));
__device__ __forceinline__ uint32_t pk_bf16(float lo, float hi) {
  union { bf16x2_t v; uint32_t u; } c;
  c.v = __builtin_amdgcn_cvt_pk_bf16_f32(lo, hi);   // RNE, 1 VALU
  return c.u;
}
#else
__device__ __forceinline__ uint32_t pk_bf16(float lo, float hi) {
  uint32_t a = __float_as_uint(lo) + 0x8000u;
  uint32_t b = __float_as_uint(hi) + 0x8000u;
  return __builtin_amdgcn_perm(b, a, 0x07060302u);
}
#endif

__device__ __forceinline__ float upk_lo(uint32_t p) { return __uint_as_float(p << 16); }
__device__ __forceinline__ float upk_hi(uint32_t p) { return __uint_as_float(p & 0xffff0000u); }

__device__ __forceinline__ uint16_t bf16_rne(float f) {
  uint32_t u = __float_as_uint(f);
  u += 0x7fffu + ((u >> 16) & 1u);
  return (uint16_t)(u >> 16);
}
__device__ __forceinline__ float bf16_dec(uint16_t h) {
  return __uint_as_float(((uint32_t)h) << 16);
}

union BFrag { short8 v; uint32_t u[4]; uint4 raw; };
union AFrag { short8 v; uint32_t u[4]; uint4 raw; };

// ---------------------------------------------------------------------------
// prep_split: W fp32 [20][64][64] -> hi frags (wsh) + residual lo frags (wsl).
// ---------------------------------------------------------------------------
__global__ void prep_split(const float* __restrict__ W,
                           uint16_t* __restrict__ wsh, uint16_t* __restrict__ wsl) {
  int idx  = blockIdx.x * 256 + threadIdx.x;   // [0, 10240)
  int l    = idx >> 9;
  int rem  = idx & 511;
  int frag = rem >> 6;
  int lane = rem & 63;
  int mt = frag >> 1, ks = frag & 1;
  int m  = lane & 15;
  int q  = lane >> 4;
  int wrow = FPERM(mt, m);
  const float* src = W + l * 4096 + wrow * 64 + 32 * ks + 8 * q;
  float4 f0 = *(const float4*)(src);
  float4 f1 = *(const float4*)(src + 4);
  float w[8] = {f0.x, f0.y, f0.z, f0.w, f1.x, f1.y, f1.z, f1.w};
  union { uint16_t s[8]; uint4 v; } oh, ol;
  #pragma unroll
  for (int j = 0; j < 8; j++) {
    uint16_t h = bf16_rne(w[j]);
    oh.s[j] = h;
    ol.s[j] = bf16_rne(w[j] - bf16_dec(h));
  }
  *(uint4*)(wsh + (size_t)idx * 8) = oh.v;
  *(uint4*)(wsl + (size_t)idx * 8) = ol.v;
}

// ---------------------------------------------------------------------------
// compose: 1 block, 128 threads. Serial 20-layer split-bf16 chain (verified).
// ---------------------------------------------------------------------------
__global__ __launch_bounds__(128, 1) void compose(
    const uint16_t* __restrict__ wsh, const uint16_t* __restrict__ wsl,
    const float* __restrict__ bias,
    uint16_t* __restrict__ afrag, float* __restrict__ vout)
{
  __shared__ float comp[65][64];                 // comp[t][i]=(M e_t + v)[i]; comp[64]=v
  __shared__ __align__(16) float biasLds[N_LAYER * 64];

  const int tid  = threadIdx.x;
  const int twv  = tid >> 6;
  const int lane = tid & 63;
  const int tl   = lane & 15;
  const int q    = lane >> 4;

  for (int i = tid; i < N_LAYER * 64; i += 128) biasLds[i] = bias[i];

  BFrag Bh[4][2], Bl[4][2];
  #pragma unroll
  for (int tb = 0; tb < 4; tb++) {
    const int tok = twv * 64 + tb * 16 + tl;
    #pragma unroll
    for (int ks = 0; ks < 2; ks++)
      #pragma unroll
      for (int p = 0; p < 4; p++) {
        const int f0 = 32 * ks + 8 * q + 2 * p;
        Bh[tb][ks].u[p] = pk_bf16(tok == f0 ? 1.0f : 0.0f, tok == f0 + 1 ? 1.0f : 0.0f);
        Bl[tb][ks].u[p] = 0u;
      }
  }

  const uint4* wph = (const uint4*)wsh;
  const uint4* wpl = (const uint4*)wsl;

  AFrag Ah[8], Al[8];
  #pragma unroll
  for (int f = 0; f < 8; f++) {
    Ah[f].raw = wph[f * 64 + lane];
    Al[f].raw = wpl[f * 64 + lane];
  }

  __syncthreads();

  floatx4 acc[4][4];
  #pragma unroll 2
  for (int l = 0; l < N_LAYER; l++) {
    const int ln = (l + 1 < N_LAYER) ? l + 1 : N_LAYER - 1;
    uint4 nh[8], nl[8];
    #pragma unroll
    for (int f = 0; f < 8; f++) {
      nh[f] = wph[(ln * 8 + f) * 64 + lane];
      nl[f] = wpl[(ln * 8 + f) * 64 + lane];
    }

    #pragma unroll
    for (int mt = 0; mt < 4; mt++) {
      floatx4 bv = *(const floatx4*)(biasLds + l * 64 + 32 * (mt >> 1) + 4 * (mt & 1) + 8 * q);
      #pragma unroll
      for (int tb = 0; tb < 4; tb++) acc[tb][mt] = bv;
    }

    #pragma unroll
    for (int ks = 0; ks < 2; ks++)
      #pragma unroll
      for (int mt = 0; mt < 4; mt++) {
        const int f = mt * 2 + ks;
        #pragma unroll
        for (int tb = 0; tb < 4; tb++) {
          acc[tb][mt] = __builtin_amdgcn_mfma_f32_16x16x32_bf16(Ah[f].v, Bh[tb][ks].v, acc[tb][mt], 0, 0, 0);
          acc[tb][mt] = __builtin_amdgcn_mfma_f32_16x16x32_bf16(Ah[f].v, Bl[tb][ks].v, acc[tb][mt], 0, 0, 0);
          acc[tb][mt] = __builtin_amdgcn_mfma_f32_16x16x32_bf16(Al[f].v, Bh[tb][ks].v, acc[tb][mt], 0, 0, 0);
        }
      }

    if (l == N_LAYER - 1) break;

    #pragma unroll
    for (int tb = 0; tb < 4; tb++)
      #pragma unroll
      for (int mt = 0; mt < 4; mt++) {
        const int ksn = mt >> 1;
        const int d   = 2 * (mt & 1);
        uint32_t u0 = pk_bf16(acc[tb][mt][0], acc[tb][mt][1]);
        uint32_t u1 = pk_bf16(acc[tb][mt][2], acc[tb][mt][3]);
        Bh[tb][ksn].u[d]     = u0;
        Bh[tb][ksn].u[d + 1] = u1;
        Bl[tb][ksn].u[d]     = pk_bf16(acc[tb][mt][0] - upk_lo(u0), acc[tb][mt][1] - upk_hi(u0));
        Bl[tb][ksn].u[d + 1] = pk_bf16(acc[tb][mt][2] - upk_lo(u1), acc[tb][mt][3] - upk_hi(u1));
      }

    #pragma unroll
    for (int f = 0; f < 8; f++) { Ah[f].raw = nh[f]; Al[f].raw = nl[f]; }
  }

  if (twv == 0) {
    #pragma unroll
    for (int tb = 0; tb < 4; tb++)
      #pragma unroll
      for (int mt = 0; mt < 4; mt++)
        *(floatx4*)&comp[tb * 16 + tl][32 * (mt >> 1) + 4 * (mt & 1) + 8 * q] = acc[tb][mt];
  } else if (tl == 0) {
    #pragma unroll
    for (int mt = 0; mt < 4; mt++)
      *(floatx4*)&comp[64][32 * (mt >> 1) + 4 * (mt & 1) + 8 * q] = acc[0][mt];
  }
  __syncthreads();

  // apply A-frags in IDENTITY row layout: A[m][k] = M[16*mt + m][k]
  for (int it = tid; it < 512; it += 128) {
    const int f  = it >> 6, ln = it & 63;
    const int mt = f >> 1,  ks = f & 1;
    const int m  = ln & 15, qq = ln >> 4;
    const int r  = 16 * mt + m;
    const float vr = comp[64][r];
    union { uint16_t s[8]; uint4 v; } o;
    #pragma unroll
    for (int j = 0; j < 8; j++) o.s[j] = bf16_rne(comp[32 * ks + 8 * qq + j][r] - vr);
    *(uint4*)(afrag + (size_t)it * 8) = o.v;
  }
  if (tid < 64) vout[tid] = comp[64][tid];
}

// ---------------------------------------------------------------------------
// apply: out = M x + v. R11 slim-register async streamer.
// Per wave (16 tokens, one-shot):
//   1) 4x global_load_lds dwordx4: linear LDS dest (j*1024 + lane*16),
//      pre-swizzled global source so LDS[tok*256 + (g^tok)*16] = x[tok][4g..]
//      -- each instr still reads a dense 1KB. (Fallback: same layout via regs.)
//   2) vmcnt(0); 4x ds_read_b128 (f32) + pk -> B-frags. addr =
//      tl*256 + ((8ks+2q+h)^tl)*16 : 8 lanes/4-bank window, conflict-free.
//   3) 8 MFMA, acc init 0 (identity row layout).
//   4) out stage (R9/R10-verified): write A = tl*256+mt*64+q*16,
//      P = A ^ (((A>>8)&7)<<4); readback lane-linear same XOR; add vreg
//      (v[tl*4..+3]); 4x dense 1KB stores.
// LDS 4KB/wave = 16KB/block; launch_bounds(256,6); 8192 blocks one-shot.
// ---------------------------------------------------------------------------
#define APPLY_BLOCKS 8192

__global__ __launch_bounds__(256, 6) void apply_affine(
    const float* __restrict__ x, const uint16_t* __restrict__ afrag,
    const float* __restrict__ vvec, float* __restrict__ out)
{
  __shared__ __align__(16) uint8_t ldsAll[4][4096];   // 4KB per wave

  const int tid  = threadIdx.x;
  const int wv   = tid >> 6;
  const int lane = tid & 63;
  const int tl   = lane & 15;
  const int q    = lane >> 4;
  uint8_t* lds = ldsAll[wv];

  const size_t tokbase = (size_t)blockIdx.x * 64 + (size_t)wv * 16;
  const float* xp = x + tokbase * 64;

  // ---- 1) stage x tile into LDS, layout P = tok*256 + (g^tok)*16
  #pragma unroll
  for (int j = 0; j < 4; j++) {
    const int tok = j * 4 + (lane >> 4);          // [0,16)
    const int g   = (lane & 15) ^ tok;            // granule index
    const float* gsrc = xp + tok * 64 + g * 4;    // 16B granule
#ifdef HAVE_GLOAD_LDS
    __builtin_amdgcn_global_load_lds(
        (const __attribute__((address_space(1))) uint32_t*)(const void*)gsrc,
        (__attribute__((address_space(3))) uint32_t*)(void*)(lds + j * 1024),
        16, 0, 0);
#else
    float4 t = *(const float4*)gsrc;
    *(float4*)(lds + j * 1024 + lane * 16) = t;
#endif
  }

  // M frags (8 KB, L1/L2-broadcast) + v slice (cols tl*4..+3)
  const uint4* wp = (const uint4*)afrag;
  AFrag Af[8];
  #pragma unroll
  for (int f = 0; f < 8; f++) Af[f].raw = wp[f * 64 + lane];
  floatx4 vreg = *(const floatx4*)(vvec + tl * 4);

#ifdef HAVE_GLOAD_LDS
  asm volatile("s_waitcnt vmcnt(0)" ::: "memory");  // x tile resident in LDS
#endif

  // ---- 2) B-frags: token tl, cols 32ks+8q..+7 (f32 -> pk bf16)
  BFrag Bf[2];
  #pragma unroll
  for (int ks = 0; ks < 2; ks++) {
    floatx4 c0 = *(const floatx4*)(lds + tl * 256 + (((8 * ks + 2 * q + 0) ^ tl) * 16));
    floatx4 c1 = *(const floatx4*)(lds + tl * 256 + (((8 * ks + 2 * q + 1) ^ tl) * 16));
    Bf[ks].u[0] = pk_bf16(c0[0], c0[1]);
    Bf[ks].u[1] = pk_bf16(c0[2], c0[3]);
    Bf[ks].u[2] = pk_bf16(c1[0], c1[1]);
    Bf[ks].u[3] = pk_bf16(c1[2], c1[3]);
  }

  // ---- 3) MFMA, acc init 0; acc[mt][i] = (Mx)[16*mt+4*q+i][tok=tl]
  floatx4 acc[4];
  #pragma unroll
  for (int mt = 0; mt < 4; mt++) acc[mt] = (floatx4){0.f, 0.f, 0.f, 0.f};
  #pragma unroll
  for (int ks = 0; ks < 2; ks++)
    #pragma unroll
    for (int mt = 0; mt < 4; mt++)
      acc[mt] = __builtin_amdgcn_mfma_f32_16x16x32_bf16(
          Af[mt * 2 + ks].v, Bf[ks].v, acc[mt], 0, 0, 0);

  // ---- 4) out stage in [0,4096) (x region dead after step 2; in-order DS)
  #pragma unroll
  for (int mt = 0; mt < 4; mt++) {
    const uint32_t A = (uint32_t)(tl * 256 + mt * 64 + q * 16);
    const uint32_t P = A ^ (((A >> 8) & 7u) << 4);
    *(floatx4*)(lds + P) = acc[mt];
  }
  #pragma unroll
  for (int j = 0; j < 4; j++) {
    const uint32_t A = (uint32_t)(j * 1024 + lane * 16);
    const uint32_t P = A ^ (((A >> 8) & 7u) << 4);
    floatx4 vd = *(const floatx4*)(lds + P);
    vd[0] += vreg[0]; vd[1] += vreg[1]; vd[2] += vreg[2]; vd[3] += vreg[3];
    *(floatx4*)(out + (tokbase + j * 4 + (lane >> 4)) * 64 + tl * 4) = vd;
  }
}

extern "C" void kernel_launch(void* const* d_in, const int* in_sizes, int n_in,
                              void* d_out, int out_size, void* d_ws, size_t ws_size,
                              hipStream_t stream) {
  (void)in_sizes; (void)n_in; (void)out_size; (void)ws_size;
  const float* x = (const float*)d_in[0];
  const float* W = (const float*)d_in[1];   // [20][64][64] fp32
  const float* b = (const float*)d_in[2];   // [20][64] fp32
  float* out = (float*)d_out;

  uint16_t* wsh   = (uint16_t*)d_ws;                     // 160 KB hi frags
  uint16_t* wsl   = (uint16_t*)((char*)d_ws + 163840);   // 160 KB lo frags
  uint16_t* afrag = (uint16_t*)((char*)d_ws + 327680);   // 8 KB composed M frags
  float*    vvec  = (float*)((char*)d_ws + 335872);      // 256 B composed v

  prep_split<<<dim3(40), dim3(256), 0, stream>>>(W, wsh, wsl);
  compose<<<dim3(1), dim3(128), 0, stream>>>(wsh, wsl, b, afrag, vvec);
  apply_affine<<<dim3(APPLY_BLOCKS), dim3(256), 0, stream>>>(x, afrag, vvec, out);
}